// Round 1
// baseline (8658.891 us; speedup 1.0000x reference)
//
#include <hip/hip_runtime.h>
#include <math.h>

#define NE   256        // embedding dim
#define NPOS 40960      // B*S*H*W = 32*64*4*5
#define XPAD 260        // row stride for Xs/Os: float4-aligned, odd in float4 units

// ---------------------------------------------------------------------------
// prep: xt[n][e] = x[b,s,e,h,w] + pos_s[s,e] + pos_h[e,h] + pos_w[e,w]
// n = ((b*64 + s)*4 + h)*5 + w
// ---------------------------------------------------------------------------
__global__ __launch_bounds__(256) void prep_kernel(
    const float* __restrict__ x, const float* __restrict__ pos_s,
    const float* __restrict__ pos_h, const float* __restrict__ pos_w,
    float* __restrict__ xt)
{
  int idx = blockIdx.x * 256 + threadIdx.x;   // [0, NPOS*NE)
  int e = idx & 255;
  int n = idx >> 8;
  int w = n % 5; int t = n / 5;
  int h = t & 3; t >>= 2;
  int s = t & 63; int b = t >> 6;
  float v = x[(((b*64 + s)*256 + e)*4 + h)*5 + w]
          + pos_s[s*256 + e] + pos_h[e*4 + h] + pos_w[e*5 + w];
  xt[idx] = v;
}

// ---------------------------------------------------------------------------
// fused axial attention for one axis.
//   T = attention length, G = groups per block, R = T*G rows staged per block.
//   axis: 0 = seq (stride 20), 1 = H (stride 5), 2 = W (stride 1)
// Each block: load R rows of xt into LDS, loop 16 heads (qkv proj -> softmax
// -> PV into Os), then out-projection (+bias) accumulated into yt.
// ---------------------------------------------------------------------------
template<int T, int G>
__global__ __launch_bounds__(256) void attn_axis(
    const float* __restrict__ xt, float* __restrict__ yt,
    const float* __restrict__ wq, const float* __restrict__ wkv,
    const float* __restrict__ wo_w, const float* __restrict__ wo_b,
    int axis)
{
  constexpr int R = T * G;
  __shared__ float Xs[R][XPAD];
  __shared__ float Os[R][XPAD];
  __shared__ float qs[R][16], ks[R][16], vs[R][16];
  __shared__ float ps[R][T + 1];
  __shared__ int   nrow[R];

  const int tid = threadIdx.x;

  if (tid < R) {
    int g  = blockIdx.x * G + tid / T;
    int ri = tid % T;
    int base, stp;
    if (axis == 0)      { int b = g / 20,  r = g % 20;                        base = b*1280 + r;            stp = 20; }
    else if (axis == 1) { int b = g / 320, r = g % 320; int s = r/5, w = r%5; base = b*1280 + s*20 + w;     stp = 5;  }
    else                { int b = g / 256, r = g % 256; int s = r/4, hh= r%4; base = b*1280 + s*20 + hh*5;  stp = 1;  }
    nrow[tid] = base + ri * stp;
  }
  __syncthreads();

  // stage input rows (coalesced float4: 64 float4 per row)
  for (int idx = tid; idx < R * (NE/4); idx += 256) {
    int r  = idx / (NE/4);
    int c4 = idx % (NE/4);
    *(float4*)(&Xs[r][c4*4]) = *(const float4*)(xt + (size_t)nrow[r]*NE + c4*4);
  }
  __syncthreads();

  const int row = tid >> 2, sub = tid & 3;
  const int gi  = row / T;

  for (int hd = 0; hd < 16; ++hd) {
    // ---- QKV projection: 12 column-quads (16 q + 16 k + 16 v) x R rows ----
    for (int task = tid; task < 12 * R; task += 256) {
      int i = task % R;
      int q = task / R;            // 0..11
      const float* wbase;
      int r0;
      if (q < 4)      { wbase = wq;  r0 = hd*16 + q*4; }
      else if (q < 8) { wbase = wkv; r0 = hd*16 + (q-4)*4; }
      else            { wbase = wkv; r0 = 256 + hd*16 + (q-8)*4; }
      const float* w0 = wbase + (size_t)r0 * NE;
      const float* w1 = w0 + NE;
      const float* w2 = w1 + NE;
      const float* w3 = w2 + NE;
      float a0=0.f, a1=0.f, a2=0.f, a3=0.f;
      #pragma unroll 4
      for (int e = 0; e < NE; e += 4) {
        float4 xv = *(const float4*)(&Xs[i][e]);
        float4 v0 = *(const float4*)(w0 + e);
        float4 v1 = *(const float4*)(w1 + e);
        float4 v2 = *(const float4*)(w2 + e);
        float4 v3 = *(const float4*)(w3 + e);
        a0 += xv.x*v0.x + xv.y*v0.y + xv.z*v0.z + xv.w*v0.w;
        a1 += xv.x*v1.x + xv.y*v1.y + xv.z*v1.z + xv.w*v1.w;
        a2 += xv.x*v2.x + xv.y*v2.y + xv.z*v2.z + xv.w*v2.w;
        a3 += xv.x*v3.x + xv.y*v3.y + xv.z*v3.z + xv.w*v3.w;
      }
      if (q < 4)      { int j = q*4;     qs[i][j]=a0; qs[i][j+1]=a1; qs[i][j+2]=a2; qs[i][j+3]=a3; }
      else if (q < 8) { int j = (q-4)*4; ks[i][j]=a0; ks[i][j+1]=a1; ks[i][j+2]=a2; ks[i][j+3]=a3; }
      else            { int j = (q-8)*4; vs[i][j]=a0; vs[i][j+1]=a1; vs[i][j+2]=a2; vs[i][j+3]=a3; }
    }
    __syncthreads();

    // ---- scores + softmax (4 lanes per row; ps holds unnormalized exp) ----
    constexpr int CMAX = (T + 3) / 4;
    float inv = 0.f;
    if (row < R) {
      float sc[CMAX];
      float m = -1e30f;
      #pragma unroll
      for (int c = 0; c < CMAX; ++c) {
        int j = sub + 4*c;
        float a = -1e30f;
        if (j < T) {
          const float* qr = &qs[row][0];
          const float* kr = &ks[gi*T + j][0];
          float acc = 0.f;
          #pragma unroll
          for (int d = 0; d < 16; ++d) acc += qr[d]*kr[d];
          a = acc * 0.25f;
        }
        sc[c] = a;
        m = fmaxf(m, a);
      }
      m = fmaxf(m, __shfl_xor(m, 1));
      m = fmaxf(m, __shfl_xor(m, 2));
      float ssum = 0.f;
      #pragma unroll
      for (int c = 0; c < CMAX; ++c) {
        int j = sub + 4*c;
        if (j < T) {
          float p = __expf(sc[c] - m);
          ps[row][j] = p;
          ssum += p;
        }
      }
      ssum += __shfl_xor(ssum, 1);
      ssum += __shfl_xor(ssum, 2);
      inv = 1.0f / ssum;
    }
    __syncthreads();

    // ---- o = P V for this head's 16 dims (4 dims per lane) ----
    if (row < R) {
      int d0 = sub * 4;
      float o0=0.f, o1=0.f, o2=0.f, o3=0.f;
      for (int j = 0; j < T; ++j) {
        float p = ps[row][j];
        const float* vr = &vs[gi*T + j][0];
        o0 += p * vr[d0+0];
        o1 += p * vr[d0+1];
        o2 += p * vr[d0+2];
        o3 += p * vr[d0+3];
      }
      Os[row][hd*16 + d0 + 0] = o0 * inv;
      Os[row][hd*16 + d0 + 1] = o1 * inv;
      Os[row][hd*16 + d0 + 2] = o2 * inv;
      Os[row][hd*16 + d0 + 3] = o3 * inv;
    }
    __syncthreads();
  }

  // ---- output projection + bias, accumulate into yt ----
  for (int task = tid; task < 64 * R; task += 256) {
    int i  = task % R;
    int q  = task / R;          // e-quad 0..63
    int e0 = q * 4;
    const float* w0 = wo_w + (size_t)e0 * NE;
    const float* w1 = w0 + NE;
    const float* w2 = w1 + NE;
    const float* w3 = w2 + NE;
    float a0 = wo_b[e0+0], a1 = wo_b[e0+1], a2 = wo_b[e0+2], a3 = wo_b[e0+3];
    #pragma unroll 4
    for (int c = 0; c < NE; c += 4) {
      float4 ov = *(const float4*)(&Os[i][c]);
      float4 v0 = *(const float4*)(w0 + c);
      float4 v1 = *(const float4*)(w1 + c);
      float4 v2 = *(const float4*)(w2 + c);
      float4 v3 = *(const float4*)(w3 + c);
      a0 += ov.x*v0.x + ov.y*v0.y + ov.z*v0.z + ov.w*v0.w;
      a1 += ov.x*v1.x + ov.y*v1.y + ov.z*v1.z + ov.w*v1.w;
      a2 += ov.x*v2.x + ov.y*v2.y + ov.z*v2.z + ov.w*v2.w;
      a3 += ov.x*v3.x + ov.y*v3.y + ov.z*v3.z + ov.w*v3.w;
    }
    float* dst = yt + (size_t)nrow[i]*NE + e0;
    float4 cur = *(float4*)dst;
    cur.x += a0; cur.y += a1; cur.z += a2; cur.w += a3;
    *(float4*)dst = cur;
  }
}

// ---------------------------------------------------------------------------
// decode: out[n] = sigmoid(dot(xt[n,:], dec_w) + dec_b); one wave per n
// ---------------------------------------------------------------------------
__global__ __launch_bounds__(256) void decode_kernel(
    const float* __restrict__ xt, const float* __restrict__ dec_w,
    const float* __restrict__ dec_b, float* __restrict__ out)
{
  int wid  = threadIdx.x >> 6;
  int lane = threadIdx.x & 63;
  int n = blockIdx.x * 4 + wid;
  float4 a = *(const float4*)(xt + (size_t)n*NE + lane*4);
  float4 b = *(const float4*)(dec_w + lane*4);
  float acc = a.x*b.x + a.y*b.y + a.z*b.z + a.w*b.w;
  #pragma unroll
  for (int m = 1; m < 64; m <<= 1) acc += __shfl_xor(acc, m);
  if (lane == 0) out[n] = 1.0f / (1.0f + __expf(-(acc + dec_b[0])));
}

// ---------------------------------------------------------------------------
extern "C" void kernel_launch(void* const* d_in, const int* in_sizes, int n_in,
                              void* d_out, int out_size, void* d_ws, size_t ws_size,
                              hipStream_t stream) {
  const float* x     = (const float*)d_in[0];
  const float* pos_s = (const float*)d_in[1];
  const float* pos_h = (const float*)d_in[2];
  const float* pos_w = (const float*)d_in[3];
  const float* wq    = (const float*)d_in[4];   // (2,3,256,256)
  const float* wkv   = (const float*)d_in[5];   // (2,3,512,256)
  const float* wo_w  = (const float*)d_in[6];   // (2,3,256,256)
  const float* wo_b  = (const float*)d_in[7];   // (2,3,256)
  const float* dec_w = (const float*)d_in[8];   // (1,256)
  const float* dec_b = (const float*)d_in[9];   // (1,)
  float* out  = (float*)d_out;

  float* buf0 = (float*)d_ws;                   // 40 MB
  float* buf1 = buf0 + (size_t)NPOS * NE;       // 40 MB

  hipMemsetAsync(buf1, 0, (size_t)NPOS * NE * sizeof(float), stream);
  prep_kernel<<<(NPOS*NE)/256, 256, 0, stream>>>(x, pos_s, pos_h, pos_w, buf0);

  for (int l = 0; l < 2; ++l) {
    const float* in = l ? buf1 : buf0;
    float*      acc = l ? buf0 : buf1;
    if (l == 1)
      hipMemsetAsync(buf0, 0, (size_t)NPOS * NE * sizeof(float), stream);
    {
      size_t o = (size_t)(l*3 + 0);
      attn_axis<64,1><<<640, 256, 0, stream>>>(in, acc,
        wq + o*256*256, wkv + o*512*256, wo_w + o*256*256, wo_b + o*256, 0);
    }
    {
      size_t o = (size_t)(l*3 + 1);
      attn_axis<4,16><<<640, 256, 0, stream>>>(in, acc,
        wq + o*256*256, wkv + o*512*256, wo_w + o*256*256, wo_b + o*256, 1);
    }
    {
      size_t o = (size_t)(l*3 + 2);
      attn_axis<5,8><<<1024, 256, 0, stream>>>(in, acc,
        wq + o*256*256, wkv + o*512*256, wo_w + o*256*256, wo_b + o*256, 2);
    }
  }

  decode_kernel<<<NPOS/4, 256, 0, stream>>>(buf0, dec_w, dec_b, out);
}

// Round 2
// 603.181 us; speedup vs baseline: 14.3554x; 14.3554x over previous
//
#include <hip/hip_runtime.h>
#include <stdint.h>

typedef unsigned short u16;
typedef u16 u16x8 __attribute__((ext_vector_type(8)));
typedef __bf16 bf16x8 __attribute__((ext_vector_type(8)));
typedef float f32x4 __attribute__((ext_vector_type(4)));

#define NE   256
#define NPOS 40960     // 32*64*4*5

__device__ __forceinline__ float bf2f(u16 h) {
  union { unsigned u; float f; } c; c.u = ((unsigned)h) << 16; return c.f;
}
__device__ __forceinline__ u16 f2bf(float f) {
  union { float f; unsigned u; } c; c.f = f;
  unsigned u = c.u;
  return (u16)((u + 0x7FFFu + ((u >> 16) & 1u)) >> 16);
}
__device__ __forceinline__ void gll16(const void* g, void* l) {
  __builtin_amdgcn_global_load_lds(
      (const __attribute__((address_space(1))) void*)g,
      (__attribute__((address_space(3))) void*)l, 16, 0, 0);
}

// ---------------------------------------------------------------------------
// prep: xb[n][e] = bf16(x[b,s,e,h,w] + pos), n = ((b*64+s)*4+h)*5+w
// one block per (b,s): read 256x20 f32 coalesced, transpose via LDS (pad 21)
// ---------------------------------------------------------------------------
__global__ __launch_bounds__(256) void prep_kernel(
    const float* __restrict__ x, const float* __restrict__ pos_s,
    const float* __restrict__ pos_h, const float* __restrict__ pos_w,
    u16* __restrict__ xb)
{
  __shared__ float Ls[256 * 21];
  const int bs = blockIdx.x;           // b*64+s
  const int s  = bs & 63;
  const int tid = threadIdx.x;
  const float* xp = x + (size_t)bs * 5120;
  for (int i = tid; i < 5120; i += 256) {
    int e = i / 20, hw = i % 20;
    int h = hw / 5, w = hw % 5;
    float v = xp[i] + pos_s[s * 256 + e] + pos_h[e * 4 + h] + pos_w[e * 5 + w];
    Ls[e * 21 + hw] = v;
  }
  __syncthreads();
  u16* op = xb + (size_t)bs * 20 * 256;
  for (int i = tid; i < 5120; i += 256) {
    int nl = i >> 8, e = i & 255;
    op[nl * 256 + e] = f2bf(Ls[e * 21 + nl]);
  }
}

// ---------------------------------------------------------------------------
// weight packing (f32 -> bf16); wqkv packed as [la][768][256]
// ---------------------------------------------------------------------------
__global__ __launch_bounds__(256) void pack_qkv(
    const float* __restrict__ wq, const float* __restrict__ wkv, u16* __restrict__ dst)
{
  int i = blockIdx.x * 256 + threadIdx.x;      // 6*768*256
  int la = i / (768 * 256);
  int rem = i - la * (768 * 256);
  int r = rem >> 8, c = rem & 255;
  float v = (r < 256) ? wq[(size_t)la * 65536 + r * 256 + c]
                      : wkv[(size_t)la * 131072 + (r - 256) * 256 + c];
  dst[i] = f2bf(v);
}

__global__ __launch_bounds__(256) void pack_wo(
    const float* __restrict__ wo, u16* __restrict__ dst)
{
  int i = blockIdx.x * 256 + threadIdx.x;      // 6*256*256
  dst[i] = f2bf(wo[i]);
}

// ---------------------------------------------------------------------------
// f32 -> bf16 convert (layer output -> next layer GEMM input)
// ---------------------------------------------------------------------------
__global__ __launch_bounds__(256) void f2b4_kernel(
    const float* __restrict__ in, u16* __restrict__ out)
{
  int i = blockIdx.x * 256 + threadIdx.x;
  float4 v = ((const float4*)in)[i];
  u16x8 dummy;
  u16 r0 = f2bf(v.x), r1 = f2bf(v.y), r2 = f2bf(v.z), r3 = f2bf(v.w);
  ushort4 r; r.x = r0; r.y = r1; r.z = r2; r.w = r3;
  ((ushort4*)out)[i] = r;
  (void)dummy;
}

// ---------------------------------------------------------------------------
// GEMM: C[M][N] = A[M][K] * B[N][K]^T   (A,B bf16; acc f32)
// MODE 0: store bf16 (QKV);  1: Cf = acc + bias;  2: Cf += acc + bias
// 128x128 tile, BK=32, 4 waves (2x2), 16x16x32 MFMA, global_load_lds staging
// ---------------------------------------------------------------------------
template<int MODE>
__global__ __launch_bounds__(256, 2) void gemm_bt(
    const u16* __restrict__ A, const u16* __restrict__ B,
    u16* __restrict__ Cb, float* __restrict__ Cf,
    const float* __restrict__ bias, int K, int ldc)
{
  __shared__ alignas(16) u16 As[128 * 32];
  __shared__ alignas(16) u16 Bs[128 * 32];
  const int tid  = threadIdx.x;
  const int bm   = blockIdx.x, bn = blockIdx.y;
  const int lane = tid & 63, w = tid >> 6;
  const int wr   = (w >> 1) * 64, wc = (w & 1) * 64;
  const int r16  = lane & 15, khi = lane >> 4;

  f32x4 acc[4][4] = {};

  const u16* gA = A + (size_t)bm * 128 * K;
  const u16* gB = B + (size_t)bn * 128 * K;

  const int nkt = K >> 5;
  for (int kt = 0; kt < nkt; ++kt) {
    const u16* tA = gA + kt * 32;
    const u16* tB = gB + kt * 32;
    for (int i = tid; i < 512; i += 256) {
      int row = i >> 2, seg = (i & 3) << 3;
      gll16(tA + (size_t)row * K + seg, (char*)As + i * 16);
      gll16(tB + (size_t)row * K + seg, (char*)Bs + i * 16);
    }
    asm volatile("s_waitcnt vmcnt(0)" ::: "memory");
    __syncthreads();

    bf16x8 af[4], bfr[4];
    #pragma unroll
    for (int m = 0; m < 4; ++m)
      af[m] = *(const bf16x8*)(As + (wr + m * 16 + r16) * 32 + khi * 8);
    #pragma unroll
    for (int n = 0; n < 4; ++n)
      bfr[n] = *(const bf16x8*)(Bs + (wc + n * 16 + r16) * 32 + khi * 8);
    #pragma unroll
    for (int m = 0; m < 4; ++m)
      #pragma unroll
      for (int n = 0; n < 4; ++n)
        acc[m][n] = __builtin_amdgcn_mfma_f32_16x16x32_bf16(af[m], bfr[n], acc[m][n], 0, 0, 0);
    __syncthreads();
  }

  const int row0 = bm * 128 + wr + khi * 4;
  const int col0 = bn * 128 + wc + r16;
  #pragma unroll
  for (int m = 0; m < 4; ++m) {
    #pragma unroll
    for (int n = 0; n < 4; ++n) {
      int c = col0 + n * 16;
      float bv = (MODE != 0) ? bias[c] : 0.f;
      #pragma unroll
      for (int j = 0; j < 4; ++j) {
        int r = row0 + m * 16 + j;
        if (MODE == 0)      Cb[(size_t)r * ldc + c] = f2bf(acc[m][n][j]);
        else if (MODE == 1) Cf[(size_t)r * ldc + c] = acc[m][n][j] + bv;
        else                Cf[(size_t)r * ldc + c] += acc[m][n][j] + bv;
      }
    }
  }
}

// ---------------------------------------------------------------------------
// attention along seq axis (T=64): one wave per (group, head)
// QKV bf16 [NPOS][768] (q|k|v each 256 = 16 heads x 16); O bf16 [NPOS][256]
// ---------------------------------------------------------------------------
__global__ __launch_bounds__(256) void attn_seq(
    const u16* __restrict__ QKV, u16* __restrict__ O)
{
  __shared__ float Ks[4][64][16];
  __shared__ float Vs[4][64][16];
  const int w = threadIdx.x >> 6, t = threadIdx.x & 63;
  const int wid = blockIdx.x * 4 + w;
  const int hd = wid & 15, g = wid >> 4;          // g in [0,640)
  const int n = (g / 20) * 1280 + (g % 20) + t * 20;
  const u16* p = QKV + (size_t)n * 768 + hd * 16;

  u16x8 q0 = *(const u16x8*)(p),       q1 = *(const u16x8*)(p + 8);
  u16x8 k0 = *(const u16x8*)(p + 256), k1 = *(const u16x8*)(p + 264);
  u16x8 v0 = *(const u16x8*)(p + 512), v1 = *(const u16x8*)(p + 520);

  float q[16];
  #pragma unroll
  for (int d = 0; d < 8; ++d) {
    q[d]     = bf2f(q0[d]) * 0.25f;
    q[d + 8] = bf2f(q1[d]) * 0.25f;
    Ks[w][t][d]     = bf2f(k0[d]);
    Ks[w][t][d + 8] = bf2f(k1[d]);
    Vs[w][t][d]     = bf2f(v0[d]);
    Vs[w][t][d + 8] = bf2f(v1[d]);
  }
  __syncthreads();

  float m = -1e30f;
  for (int j = 0; j < 64; ++j) {
    float s = 0.f;
    #pragma unroll
    for (int d = 0; d < 16; ++d) s += q[d] * Ks[w][j][d];
    m = fmaxf(m, s);
  }
  float sum = 0.f;
  float o[16];
  #pragma unroll
  for (int d = 0; d < 16; ++d) o[d] = 0.f;
  for (int j = 0; j < 64; ++j) {
    float s = 0.f;
    #pragma unroll
    for (int d = 0; d < 16; ++d) s += q[d] * Ks[w][j][d];
    float pj = __expf(s - m);
    sum += pj;
    #pragma unroll
    for (int d = 0; d < 16; ++d) o[d] += pj * Vs[w][j][d];
  }
  float inv = 1.0f / sum;
  u16x8 r0, r1;
  #pragma unroll
  for (int d = 0; d < 8; ++d) {
    r0[d] = f2bf(o[d] * inv);
    r1[d] = f2bf(o[d + 8] * inv);
  }
  u16* po = O + (size_t)n * 256 + hd * 16;
  *(u16x8*)(po)     = r0;
  *(u16x8*)(po + 8) = r1;
}

// ---------------------------------------------------------------------------
// attention along H (T=4, stride 5) or W (T=5, stride 1): thread per (n, head)
// ---------------------------------------------------------------------------
template<int AXIS, int T>
__global__ __launch_bounds__(256) void attn_small(
    const u16* __restrict__ QKV, u16* __restrict__ O)
{
  const int tg = blockIdx.x * 256 + threadIdx.x;   // n*16 + hd
  const int hd = tg & 15, n = tg >> 4;
  int base, stp;
  if (AXIS == 1) { int h = (n % 20) / 5; base = n - h * 5; stp = 5; }
  else           { int w5 = n % 5;       base = n - w5;    stp = 1; }

  const u16* qp = QKV + (size_t)n * 768 + hd * 16;
  u16x8 q0 = *(const u16x8*)(qp), q1 = *(const u16x8*)(qp + 8);
  float q[16];
  #pragma unroll
  for (int d = 0; d < 8; ++d) { q[d] = bf2f(q0[d]) * 0.25f; q[d + 8] = bf2f(q1[d]) * 0.25f; }

  float s[T];
  float m = -1e30f;
  #pragma unroll
  for (int j = 0; j < T; ++j) {
    const u16* kp = QKV + (size_t)(base + j * stp) * 768 + 256 + hd * 16;
    u16x8 k0 = *(const u16x8*)(kp), k1 = *(const u16x8*)(kp + 8);
    float a = 0.f;
    #pragma unroll
    for (int d = 0; d < 8; ++d) a += q[d] * bf2f(k0[d]) + q[d + 8] * bf2f(k1[d]);
    s[j] = a;
    m = fmaxf(m, a);
  }
  float sum = 0.f;
  float o[16];
  #pragma unroll
  for (int d = 0; d < 16; ++d) o[d] = 0.f;
  #pragma unroll
  for (int j = 0; j < T; ++j) {
    float pj = __expf(s[j] - m);
    sum += pj;
    const u16* vp = QKV + (size_t)(base + j * stp) * 768 + 512 + hd * 16;
    u16x8 w0 = *(const u16x8*)(vp), w1 = *(const u16x8*)(vp + 8);
    #pragma unroll
    for (int d = 0; d < 8; ++d) { o[d] += pj * bf2f(w0[d]); o[d + 8] += pj * bf2f(w1[d]); }
  }
  float inv = 1.0f / sum;
  u16x8 r0, r1;
  #pragma unroll
  for (int d = 0; d < 8; ++d) { r0[d] = f2bf(o[d] * inv); r1[d] = f2bf(o[d + 8] * inv); }
  u16* po = O + (size_t)n * 256 + hd * 16;
  *(u16x8*)(po)     = r0;
  *(u16x8*)(po + 8) = r1;
}

// ---------------------------------------------------------------------------
// decode: out[n] = sigmoid(dot(acc[n,:], dec_w) + dec_b); one wave per n
// ---------------------------------------------------------------------------
__global__ __launch_bounds__(256) void decode_kernel(
    const float* __restrict__ xt, const float* __restrict__ dec_w,
    const float* __restrict__ dec_b, float* __restrict__ out)
{
  int wid  = threadIdx.x >> 6;
  int lane = threadIdx.x & 63;
  int n = blockIdx.x * 4 + wid;
  float4 a = *(const float4*)(xt + (size_t)n * NE + lane * 4);
  float4 b = *(const float4*)(dec_w + lane * 4);
  float acc = a.x * b.x + a.y * b.y + a.z * b.z + a.w * b.w;
  #pragma unroll
  for (int m = 1; m < 64; m <<= 1) acc += __shfl_xor(acc, m);
  if (lane == 0) out[n] = 1.0f / (1.0f + __expf(-(acc + dec_b[0])));
}

// ---------------------------------------------------------------------------
extern "C" void kernel_launch(void* const* d_in, const int* in_sizes, int n_in,
                              void* d_out, int out_size, void* d_ws, size_t ws_size,
                              hipStream_t stream) {
  const float* x     = (const float*)d_in[0];
  const float* pos_s = (const float*)d_in[1];
  const float* pos_h = (const float*)d_in[2];
  const float* pos_w = (const float*)d_in[3];
  const float* wq    = (const float*)d_in[4];   // (2,3,256,256)
  const float* wkv   = (const float*)d_in[5];   // (2,3,512,256)
  const float* wo_w  = (const float*)d_in[6];   // (2,3,256,256)
  const float* wo_b  = (const float*)d_in[7];   // (2,3,256)
  const float* dec_w = (const float*)d_in[8];   // (1,256)
  const float* dec_b = (const float*)d_in[9];   // (1,)
  float* out = (float*)d_out;

  char* ws = (char*)d_ws;
  float* acc = (float*)ws;                      // 40960*256*4  = 41943040
  u16*   xb  = (u16*)(ws + 41943040);           // 40960*256*2  = 20971520
  u16*   Ob  = (u16*)(ws + 62914560);           // 40960*256*2  = 20971520
  u16*   QKV = (u16*)(ws + 83886080);           // 40960*768*2  = 62914560
  u16*   wqp = (u16*)(ws + 146800640);          // 6*768*256*2  = 2359296
  u16*   wop = (u16*)(ws + 149159936);          // 6*256*256*2  = 786432

  prep_kernel<<<2048, 256, 0, stream>>>(x, pos_s, pos_h, pos_w, xb);
  pack_qkv<<<4608, 256, 0, stream>>>(wq, wkv, wqp);
  pack_wo<<<1536, 256, 0, stream>>>(wo_w, wop);

  for (int l = 0; l < 2; ++l) {
    for (int a = 0; a < 3; ++a) {
      int la = l * 3 + a;
      gemm_bt<0><<<dim3(320, 6), 256, 0, stream>>>(
          xb, wqp + (size_t)la * 196608, QKV, nullptr, nullptr, 256, 768);
      if (a == 0)      attn_seq<<<2560, 256, 0, stream>>>(QKV, Ob);
      else if (a == 1) attn_small<1, 4><<<2560, 256, 0, stream>>>(QKV, Ob);
      else             attn_small<2, 5><<<2560, 256, 0, stream>>>(QKV, Ob);
      if (a == 0)
        gemm_bt<1><<<dim3(320, 2), 256, 0, stream>>>(
            Ob, wop + (size_t)la * 65536, nullptr, acc, wo_b + la * 256, 256, 256);
      else
        gemm_bt<2><<<dim3(320, 2), 256, 0, stream>>>(
            Ob, wop + (size_t)la * 65536, nullptr, acc, wo_b + la * 256, 256, 256);
    }
    if (l == 0) f2b4_kernel<<<10240, 256, 0, stream>>>(acc, xb);
  }

  decode_kernel<<<NPOS / 4, 256, 0, stream>>>(acc, dec_w, dec_b, out);
}

// Round 3
// 385.356 us; speedup vs baseline: 22.4698x; 1.5653x over previous
//
#include <hip/hip_runtime.h>
#include <stdint.h>

typedef unsigned short u16;
typedef u16 u16x8 __attribute__((ext_vector_type(8)));
typedef __bf16 bf16x8 __attribute__((ext_vector_type(8)));
typedef float f32x4 __attribute__((ext_vector_type(4)));
typedef float f32x16 __attribute__((ext_vector_type(16)));

#define NE   256
#define NPOS 40960     // 32*64*4*5

__device__ __forceinline__ float bf2f(u16 h) {
  union { unsigned u; float f; } c; c.u = ((unsigned)h) << 16; return c.f;
}
__device__ __forceinline__ u16 f2bf(float f) {
  union { float f; unsigned u; } c; c.f = f;
  unsigned u = c.u;
  return (u16)((u + 0x7FFFu + ((u >> 16) & 1u)) >> 16);
}
__device__ __forceinline__ unsigned pkbf(float a, float b) {
  unsigned r;
  asm("v_cvt_pk_bf16_f32 %0, %1, %2" : "=v"(r) : "v"(a), "v"(b));
  return r;
}
__device__ __forceinline__ void gll16(const void* g, void* l) {
  __builtin_amdgcn_global_load_lds(
      (const __attribute__((address_space(1))) void*)g,
      (__attribute__((address_space(3))) void*)l, 16, 0, 0);
}

// ---------------------------------------------------------------------------
// prep: xb[n][e] = bf16(x[b,s,e,h,w] + pos), n = ((b*64+s)*4+h)*5+w
// ---------------------------------------------------------------------------
__global__ __launch_bounds__(256) void prep_kernel(
    const float* __restrict__ x, const float* __restrict__ pos_s,
    const float* __restrict__ pos_h, const float* __restrict__ pos_w,
    u16* __restrict__ xb)
{
  __shared__ float Ls[256 * 21];
  const int bs = blockIdx.x;           // b*64+s
  const int s  = bs & 63;
  const int tid = threadIdx.x;
  const float* xp = x + (size_t)bs * 5120;
  for (int i = tid; i < 5120; i += 256) {
    int e = i / 20, hw = i % 20;
    int h = hw / 5, w = hw % 5;
    float v = xp[i] + pos_s[s * 256 + e] + pos_h[e * 4 + h] + pos_w[e * 5 + w];
    Ls[e * 21 + hw] = v;
  }
  __syncthreads();
  u16* op = xb + (size_t)bs * 20 * 256;
  for (int i = tid; i < 5120; i += 256) {
    int nl = i >> 8, e = i & 255;
    op[nl * 256 + e] = f2bf(Ls[e * 21 + nl]);
  }
}

// ---------------------------------------------------------------------------
// weight packing
// ---------------------------------------------------------------------------
__global__ __launch_bounds__(256) void pack_qkv(
    const float* __restrict__ wq, const float* __restrict__ wkv, u16* __restrict__ dst)
{
  int i = blockIdx.x * 256 + threadIdx.x;      // 6*768*256
  int la = i / (768 * 256);
  int rem = i - la * (768 * 256);
  int r = rem >> 8, c = rem & 255;
  float v = (r < 256) ? wq[(size_t)la * 65536 + r * 256 + c]
                      : wkv[(size_t)la * 131072 + (r - 256) * 256 + c];
  dst[i] = f2bf(v);
}

// merged out-proj weights: dst[l][out][a*256+in] = wo_w[l][a][out][in]
__global__ __launch_bounds__(256) void pack_wo(
    const float* __restrict__ wo, u16* __restrict__ dst)
{
  int i = blockIdx.x * 256 + threadIdx.x;      // 2*256*768
  int l = i / 196608;
  int rem = i - l * 196608;
  int out = rem / 768, k = rem % 768;
  int a = k >> 8, in = k & 255;
  dst[i] = f2bf(wo[(size_t)(((l * 3 + a) * 256) + out) * 256 + in]);
}

__global__ __launch_bounds__(256) void pack_bias(
    const float* __restrict__ wo_b, float* __restrict__ bsum)
{
  int i = blockIdx.x * 256 + threadIdx.x;      // 512
  if (i < 512) {
    int l = i >> 8, c = i & 255;
    bsum[i] = wo_b[(l * 3 + 0) * 256 + c] + wo_b[(l * 3 + 1) * 256 + c]
            + wo_b[(l * 3 + 2) * 256 + c];
  }
}

// ---------------------------------------------------------------------------
// GEMM: C[M][N] = A[M][K] * B[N][K]^T   (A,B bf16; acc f32)
// MODE 0: store bf16;  1: Cf = acc + bias;  3: Cb = bf16(acc + bias)
// ---------------------------------------------------------------------------
template<int MODE>
__global__ __launch_bounds__(256, 2) void gemm_bt(
    const u16* __restrict__ A, const u16* __restrict__ B,
    u16* __restrict__ Cb, float* __restrict__ Cf,
    const float* __restrict__ bias, int K, int ldc)
{
  __shared__ alignas(16) u16 As[128 * 32];
  __shared__ alignas(16) u16 Bs[128 * 32];
  const int tid  = threadIdx.x;
  const int bm   = blockIdx.x, bn = blockIdx.y;
  const int lane = tid & 63, w = tid >> 6;
  const int wr   = (w >> 1) * 64, wc = (w & 1) * 64;
  const int r16  = lane & 15, khi = lane >> 4;

  f32x4 acc[4][4] = {};

  const u16* gA = A + (size_t)bm * 128 * K;
  const u16* gB = B + (size_t)bn * 128 * K;

  const int nkt = K >> 5;
  for (int kt = 0; kt < nkt; ++kt) {
    const u16* tA = gA + kt * 32;
    const u16* tB = gB + kt * 32;
    for (int i = tid; i < 512; i += 256) {
      int row = i >> 2, seg = (i & 3) << 3;
      gll16(tA + (size_t)row * K + seg, (char*)As + i * 16);
      gll16(tB + (size_t)row * K + seg, (char*)Bs + i * 16);
    }
    asm volatile("s_waitcnt vmcnt(0)" ::: "memory");
    __syncthreads();

    bf16x8 af[4], bfr[4];
    #pragma unroll
    for (int m = 0; m < 4; ++m)
      af[m] = *(const bf16x8*)(As + (wr + m * 16 + r16) * 32 + khi * 8);
    #pragma unroll
    for (int n = 0; n < 4; ++n)
      bfr[n] = *(const bf16x8*)(Bs + (wc + n * 16 + r16) * 32 + khi * 8);
    #pragma unroll
    for (int m = 0; m < 4; ++m)
      #pragma unroll
      for (int n = 0; n < 4; ++n)
        acc[m][n] = __builtin_amdgcn_mfma_f32_16x16x32_bf16(af[m], bfr[n], acc[m][n], 0, 0, 0);
    __syncthreads();
  }

  const int row0 = bm * 128 + wr + khi * 4;
  const int col0 = bn * 128 + wc + r16;
  #pragma unroll
  for (int m = 0; m < 4; ++m) {
    #pragma unroll
    for (int n = 0; n < 4; ++n) {
      int c = col0 + n * 16;
      float bv = (MODE != 0) ? bias[c] : 0.f;
      #pragma unroll
      for (int j = 0; j < 4; ++j) {
        int r = row0 + m * 16 + j;
        if (MODE == 0)      Cb[(size_t)r * ldc + c] = f2bf(acc[m][n][j]);
        else if (MODE == 1) Cf[(size_t)r * ldc + c] = acc[m][n][j] + bv;
        else                Cb[(size_t)r * ldc + c] = f2bf(acc[m][n][j] + bv);
      }
    }
  }
}

// ---------------------------------------------------------------------------
// seq-axis attention via MFMA. One wave = one (group g, head hd).
// QKV [NPOS][768] bf16 (q|k|v). Writes Ob cols 0..255 (stride 768).
// S^T = K*Q^T with mfma_f32_32x32x16_bf16 (D=16 = MFMA K); softmax lane-local
// (query = lane&31); P -> B-frag via v_cvt_pk_bf16_f32 + shfl_xor(32);
// O^T = V^T * P^T. No LDS, no barriers.
// ---------------------------------------------------------------------------
__global__ __launch_bounds__(256) void attn_seq_mfma(
    const u16* __restrict__ QKV, u16* __restrict__ Ob)
{
  const int w = threadIdx.x >> 6, lane = threadIdx.x & 63;
  const int wid = blockIdx.x * 4 + w;
  const int hd = wid & 15, g = wid >> 4;          // g in [0,640)
  const int gb = g / 20, gr = g % 20;
  const int nbase = gb * 1280 + gr;               // + pos*20
  const int lo = lane & 31, hi = lane >> 5;

  // K as A-frag (row=key=lo+32t, k=dim=hi*8+j), Q as B-frag (col=query, k=dim)
  bf16x8 kf[2], qf[2];
  #pragma unroll
  for (int t = 0; t < 2; ++t) {
    size_t r = (size_t)(nbase + (lo + 32 * t) * 20) * 768;
    kf[t] = *(const bf16x8*)(QKV + r + 256 + hd * 16 + hi * 8);
    qf[t] = *(const bf16x8*)(QKV + r +       hd * 16 + hi * 8);
  }
  // V^T as A-frag for PV: row=dim=lo (>=16 unused), k=key=c*16+hi*8+j
  union { u16 a[8]; bf16x8 v; } vt[4];
  #pragma unroll
  for (int c = 0; c < 4; ++c)
    #pragma unroll
    for (int j = 0; j < 8; ++j)
      vt[c].a[j] = QKV[(size_t)(nbase + (c * 16 + hi * 8 + j) * 20) * 768
                       + 512 + hd * 16 + lo];

  f32x16 s00 = {}, s10 = {}, s01 = {}, s11 = {};   // s[kt][qt]
  s00 = __builtin_amdgcn_mfma_f32_32x32x16_bf16(kf[0], qf[0], s00, 0, 0, 0);
  s10 = __builtin_amdgcn_mfma_f32_32x32x16_bf16(kf[1], qf[0], s10, 0, 0, 0);
  s01 = __builtin_amdgcn_mfma_f32_32x32x16_bf16(kf[0], qf[1], s01, 0, 0, 0);
  s11 = __builtin_amdgcn_mfma_f32_32x32x16_bf16(kf[1], qf[1], s11, 0, 0, 0);

  auto run_qt = [&](f32x16 t0, f32x16 t1, int qt) {
    // softmax over 64 keys: 32 local regs + partner lane (lane^32)
    float m = -1e30f;
    #pragma unroll
    for (int r = 0; r < 16; ++r) { m = fmaxf(m, t0[r]); m = fmaxf(m, t1[r]); }
    m = fmaxf(m, __shfl_xor(m, 32));
    const float C = 0.36067376022f;                // 0.25 * log2(e)
    float mc = m * C;
    float sum = 0.f;
    #pragma unroll
    for (int r = 0; r < 16; ++r) {
      float p0 = __builtin_amdgcn_exp2f(t0[r] * C - mc);
      float p1 = __builtin_amdgcn_exp2f(t1[r] * C - mc);
      t0[r] = p0; t1[r] = p1; sum += p0; sum += p1;
    }
    sum += __shfl_xor(sum, 32);
    float inv = __builtin_amdgcn_rcpf(sum);
    #pragma unroll
    for (int r = 0; r < 16; ++r) { t0[r] *= inv; t1[r] *= inv; }

    // PV: O^T[qt] = sum_c Vt[c] * P^T[c]   (4 chunks of 16 keys)
    f32x16 oa = {};
    // chunk assembly: dest lane needs P[q=lo][key = c*16 + hi*8 + j]
    //   j=0..3 from hi_src=0 regs rb+4*hi..+3; j=4..7 from hi_src=1 same regs
    #pragma unroll
    for (int c = 0; c < 4; ++c) {
      const int rb = 8 * (c & 1);
      const f32x16& tt = (c < 2) ? t0 : t1;
      unsigned X0 = pkbf(tt[rb + 0], tt[rb + 1]);
      unsigned X1 = pkbf(tt[rb + 2], tt[rb + 3]);
      unsigned Y0 = pkbf(tt[rb + 4], tt[rb + 5]);
      unsigned Y1 = pkbf(tt[rb + 6], tt[rb + 7]);
      unsigned X0p = __shfl_xor((int)X0, 32), X1p = __shfl_xor((int)X1, 32);
      unsigned Y0p = __shfl_xor((int)Y0, 32), Y1p = __shfl_xor((int)Y1, 32);
      union { unsigned u[4]; bf16x8 v; } pf;
      pf.u[0] = hi ? Y0p : X0;
      pf.u[1] = hi ? Y1p : X1;
      pf.u[2] = hi ? Y0  : X0p;
      pf.u[3] = hi ? Y1  : X1p;
      oa = __builtin_amdgcn_mfma_f32_32x32x16_bf16(vt[c].v, pf.v, oa, 0, 0, 0);
    }
    // oa rows (dims): reg r -> dim (r&3) + 8*(r>>2) + 4*hi  (regs 0..7 valid)
    unsigned P0 = pkbf(oa[0], oa[1]);
    unsigned P1 = pkbf(oa[2], oa[3]);
    unsigned P2 = pkbf(oa[4], oa[5]);
    unsigned P3 = pkbf(oa[6], oa[7]);
    unsigned sP0 = __shfl_xor((int)P0, 32), sP1 = __shfl_xor((int)P1, 32);
    unsigned sP2 = __shfl_xor((int)P2, 32), sP3 = __shfl_xor((int)P3, 32);
    union { unsigned u[4]; u16x8 v; } ov;
    ov.u[0] = hi ? sP2 : P0;
    ov.u[1] = hi ? sP3 : P1;
    ov.u[2] = hi ? P2  : sP0;
    ov.u[3] = hi ? P3  : sP1;
    u16* po = Ob + (size_t)(nbase + (qt * 32 + lo) * 20) * 768 + hd * 16 + hi * 8;
    *(u16x8*)po = ov.v;
  };
  run_qt(s00, s10, 0);
  run_qt(s01, s11, 1);
}

// ---------------------------------------------------------------------------
// attention along H (T=4, stride 5) or W (T=5, stride 1): thread per (n, head)
// writes to Ob (caller offsets by a*256), row stride 768
// ---------------------------------------------------------------------------
template<int AXIS, int T>
__global__ __launch_bounds__(256) void attn_small(
    const u16* __restrict__ QKV, u16* __restrict__ O)
{
  const int tg = blockIdx.x * 256 + threadIdx.x;   // n*16 + hd
  const int hd = tg & 15, n = tg >> 4;
  int base, stp;
  if (AXIS == 1) { int h = (n % 20) / 5; base = n - h * 5; stp = 5; }
  else           { int w5 = n % 5;       base = n - w5;    stp = 1; }

  const u16* qp = QKV + (size_t)n * 768 + hd * 16;
  u16x8 q0 = *(const u16x8*)(qp), q1 = *(const u16x8*)(qp + 8);
  float q[16];
  #pragma unroll
  for (int d = 0; d < 8; ++d) { q[d] = bf2f(q0[d]) * 0.25f; q[d + 8] = bf2f(q1[d]) * 0.25f; }

  float s[T];
  float m = -1e30f;
  #pragma unroll
  for (int j = 0; j < T; ++j) {
    const u16* kp = QKV + (size_t)(base + j * stp) * 768 + 256 + hd * 16;
    u16x8 k0 = *(const u16x8*)(kp), k1 = *(const u16x8*)(kp + 8);
    float a = 0.f;
    #pragma unroll
    for (int d = 0; d < 8; ++d) a += q[d] * bf2f(k0[d]) + q[d + 8] * bf2f(k1[d]);
    s[j] = a;
    m = fmaxf(m, a);
  }
  float sum = 0.f;
  float o[16];
  #pragma unroll
  for (int d = 0; d < 16; ++d) o[d] = 0.f;
  #pragma unroll
  for (int j = 0; j < T; ++j) {
    float pj = __expf(s[j] - m);
    sum += pj;
    const u16* vp = QKV + (size_t)(base + j * stp) * 768 + 512 + hd * 16;
    u16x8 w0 = *(const u16x8*)(vp), w1 = *(const u16x8*)(vp + 8);
    #pragma unroll
    for (int d = 0; d < 8; ++d) { o[d] += pj * bf2f(w0[d]); o[d + 8] += pj * bf2f(w1[d]); }
  }
  float inv = 1.0f / sum;
  u16x8 r0, r1;
  #pragma unroll
  for (int d = 0; d < 8; ++d) { r0[d] = f2bf(o[d] * inv); r1[d] = f2bf(o[d + 8] * inv); }
  u16* po = O + (size_t)n * 768 + hd * 16;
  *(u16x8*)(po)     = r0;
  *(u16x8*)(po + 8) = r1;
}

// ---------------------------------------------------------------------------
// decode: out[n] = sigmoid(dot(acc[n,:], dec_w) + dec_b); one wave per n
// ---------------------------------------------------------------------------
__global__ __launch_bounds__(256) void decode_kernel(
    const float* __restrict__ xt, const float* __restrict__ dec_w,
    const float* __restrict__ dec_b, float* __restrict__ out)
{
  int wid  = threadIdx.x >> 6;
  int lane = threadIdx.x & 63;
  int n = blockIdx.x * 4 + wid;
  float4 a = *(const float4*)(xt + (size_t)n * NE + lane * 4);
  float4 b = *(const float4*)(dec_w + lane * 4);
  float acc = a.x * b.x + a.y * b.y + a.z * b.z + a.w * b.w;
  #pragma unroll
  for (int m = 1; m < 64; m <<= 1) acc += __shfl_xor(acc, m);
  if (lane == 0) out[n] = 1.0f / (1.0f + __expf(-(acc + dec_b[0])));
}

// ---------------------------------------------------------------------------
extern "C" void kernel_launch(void* const* d_in, const int* in_sizes, int n_in,
                              void* d_out, int out_size, void* d_ws, size_t ws_size,
                              hipStream_t stream) {
  const float* x     = (const float*)d_in[0];
  const float* pos_s = (const float*)d_in[1];
  const float* pos_h = (const float*)d_in[2];
  const float* pos_w = (const float*)d_in[3];
  const float* wq    = (const float*)d_in[4];   // (2,3,256,256)
  const float* wkv   = (const float*)d_in[5];   // (2,3,512,256)
  const float* wo_w  = (const float*)d_in[6];   // (2,3,256,256)
  const float* wo_b  = (const float*)d_in[7];   // (2,3,256)
  const float* dec_w = (const float*)d_in[8];   // (1,256)
  const float* dec_b = (const float*)d_in[9];   // (1,)
  float* out = (float*)d_out;

  char* ws = (char*)d_ws;
  u16*   xb   = (u16*)ws;                        // 40960*256*2  = 20,971,520
  u16*   Ob   = (u16*)(ws + 20971520);           // 40960*768*2  = 62,914,560
  u16*   QKV  = (u16*)(ws + 83886080);           // 40960*768*2 + 128 pad
  u16*   wqp  = (u16*)(ws + 146800768);          // 6*768*256*2  = 2,359,296
  u16*   wop  = (u16*)(ws + 149160064);          // 2*256*768*2  = 786,432
  float* bsum = (float*)(ws + 149946496);        // 512*4 = 2048
  float* acc  = (float*)(ws + 83886080);         // alias QKV (free by then)

  prep_kernel<<<2048, 256, 0, stream>>>(x, pos_s, pos_h, pos_w, xb);
  pack_qkv<<<4608, 256, 0, stream>>>(wq, wkv, wqp);
  pack_wo<<<1536, 256, 0, stream>>>(wo_w, wop);
  pack_bias<<<2, 256, 0, stream>>>(wo_b, bsum);

  for (int l = 0; l < 2; ++l) {
    for (int a = 0; a < 3; ++a) {
      int la = l * 3 + a;
      gemm_bt<0><<<dim3(320, 6), 256, 0, stream>>>(
          xb, wqp + (size_t)la * 196608, QKV, nullptr, nullptr, 256, 768);
      if (a == 0)      attn_seq_mfma<<<2560, 256, 0, stream>>>(QKV, Ob);
      else if (a == 1) attn_small<1, 4><<<2560, 256, 0, stream>>>(QKV, Ob + 256);
      else             attn_small<2, 5><<<2560, 256, 0, stream>>>(QKV, Ob + 512);
    }
    if (l == 0)
      gemm_bt<3><<<dim3(320, 2), 256, 0, stream>>>(
          Ob, wop, xb, nullptr, bsum, 768, 256);
    else
      gemm_bt<1><<<dim3(320, 2), 256, 0, stream>>>(
          Ob, wop + 196608, nullptr, acc, bsum + 256, 768, 256);
  }

  decode_kernel<<<NPOS / 4, 256, 0, stream>>>(acc, dec_w, dec_b, out);
}

// Round 4
// 367.248 us; speedup vs baseline: 23.5778x; 1.0493x over previous
//
#include <hip/hip_runtime.h>
#include <stdint.h>

typedef unsigned short u16;
typedef u16 u16x8 __attribute__((ext_vector_type(8)));
typedef __bf16 bf16x8 __attribute__((ext_vector_type(8)));
typedef float f32x4 __attribute__((ext_vector_type(4)));
typedef float f32x16 __attribute__((ext_vector_type(16)));

#define NE   256
#define NPOS 40960     // 32*64*4*5
#define QLD  1536      // QKV row stride

__device__ __forceinline__ float bf2f(u16 h) {
  union { unsigned u; float f; } c; c.u = ((unsigned)h) << 16; return c.f;
}
__device__ __forceinline__ u16 f2bf(float f) {
  union { float f; unsigned u; } c; c.f = f;
  unsigned u = c.u;
  return (u16)((u + 0x7FFFu + ((u >> 16) & 1u)) >> 16);
}
__device__ __forceinline__ unsigned pkbf(float a, float b) {
  unsigned r;
  asm("v_cvt_pk_bf16_f32 %0, %1, %2" : "=v"(r) : "v"(a), "v"(b));
  return r;
}
__device__ __forceinline__ void gll16(const void* g, void* l) {
  __builtin_amdgcn_global_load_lds(
      (const __attribute__((address_space(1))) void*)g,
      (__attribute__((address_space(3))) void*)l, 16, 0, 0);
}

// ---------------------------------------------------------------------------
// prep: xb[n][e] = bf16(x[b,s,e,h,w] + pos), n = ((b*64+s)*4+h)*5+w
// ---------------------------------------------------------------------------
__global__ __launch_bounds__(256) void prep_kernel(
    const float* __restrict__ x, const float* __restrict__ pos_s,
    const float* __restrict__ pos_h, const float* __restrict__ pos_w,
    u16* __restrict__ xb)
{
  __shared__ float Ls[256 * 21];
  const int bs = blockIdx.x;           // b*64+s
  const int s  = bs & 63;
  const int tid = threadIdx.x;
  const float* xp = x + (size_t)bs * 5120;
  for (int i = tid; i < 5120; i += 256) {
    int e = i / 20, hw = i % 20;
    int h = hw / 5, w = hw % 5;
    float v = xp[i] + pos_s[s * 256 + e] + pos_h[e * 4 + h] + pos_w[e * 5 + w];
    Ls[e * 21 + hw] = v;
  }
  __syncthreads();
  u16* op = xb + (size_t)bs * 20 * 256;
  for (int i = tid; i < 5120; i += 256) {
    int nl = i >> 8, e = i & 255;
    op[nl * 256 + e] = f2bf(Ls[e * 21 + nl]);
  }
}

// ---------------------------------------------------------------------------
// weight packing; wq rows scaled by 0.25 (attention SCALE folded in)
// ---------------------------------------------------------------------------
__global__ __launch_bounds__(256) void pack_qkv(
    const float* __restrict__ wq, const float* __restrict__ wkv, u16* __restrict__ dst)
{
  int i = blockIdx.x * 256 + threadIdx.x;      // 6*768*256
  int la = i / (768 * 256);
  int rem = i - la * (768 * 256);
  int r = rem >> 8, c = rem & 255;
  float v = (r < 256) ? wq[(size_t)la * 65536 + r * 256 + c] * 0.25f
                      : wkv[(size_t)la * 131072 + (r - 256) * 256 + c];
  dst[i] = f2bf(v);
}

// merged out-proj weights: dst[l][out][a*256+in] = wo_w[l][a][out][in]
__global__ __launch_bounds__(256) void pack_wo(
    const float* __restrict__ wo, u16* __restrict__ dst)
{
  int i = blockIdx.x * 256 + threadIdx.x;      // 2*256*768
  int l = i / 196608;
  int rem = i - l * 196608;
  int out = rem / 768, k = rem % 768;
  int a = k >> 8, in = k & 255;
  dst[i] = f2bf(wo[(size_t)(((l * 3 + a) * 256) + out) * 256 + in]);
}

__global__ __launch_bounds__(256) void pack_bias(
    const float* __restrict__ wo_b, float* __restrict__ bsum)
{
  int i = blockIdx.x * 256 + threadIdx.x;      // 512
  if (i < 512) {
    int l = i >> 8, c = i & 255;
    bsum[i] = wo_b[(l * 3 + 0) * 256 + c] + wo_b[(l * 3 + 1) * 256 + c]
            + wo_b[(l * 3 + 2) * 256 + c];
  }
}

// ---------------------------------------------------------------------------
// GEMM: C[M][N] = A[M][K] * B[N][K]^T   (A,B bf16; acc f32)
// MODE 0: store bf16 at ldc; 3: Cb = bf16(acc+bias); 4: fused decode partial
// ---------------------------------------------------------------------------
template<int MODE>
__global__ __launch_bounds__(256, 2) void gemm_bt(
    const u16* __restrict__ A, const u16* __restrict__ B,
    u16* __restrict__ Cb, const float* __restrict__ bias,
    const float* __restrict__ dw, float* __restrict__ logit,
    int K, int ldc)
{
  __shared__ alignas(16) u16 As[128 * 32];
  __shared__ alignas(16) u16 Bs[128 * 32];
  const int tid  = threadIdx.x;
  const int bm   = blockIdx.x, bn = blockIdx.y;
  const int lane = tid & 63, w = tid >> 6;
  const int wr   = (w >> 1) * 64, wc = (w & 1) * 64;
  const int r16  = lane & 15, khi = lane >> 4;

  f32x4 acc[4][4] = {};

  const u16* gA = A + (size_t)bm * 128 * K;
  const u16* gB = B + (size_t)bn * 128 * K;

  const int nkt = K >> 5;
  for (int kt = 0; kt < nkt; ++kt) {
    const u16* tA = gA + kt * 32;
    const u16* tB = gB + kt * 32;
    for (int i = tid; i < 512; i += 256) {
      int row = i >> 2, seg = (i & 3) << 3;
      gll16(tA + (size_t)row * K + seg, (char*)As + i * 16);
      gll16(tB + (size_t)row * K + seg, (char*)Bs + i * 16);
    }
    asm volatile("s_waitcnt vmcnt(0)" ::: "memory");
    __syncthreads();

    bf16x8 af[4], bfr[4];
    #pragma unroll
    for (int m = 0; m < 4; ++m)
      af[m] = *(const bf16x8*)(As + (wr + m * 16 + r16) * 32 + khi * 8);
    #pragma unroll
    for (int n = 0; n < 4; ++n)
      bfr[n] = *(const bf16x8*)(Bs + (wc + n * 16 + r16) * 32 + khi * 8);
    #pragma unroll
    for (int m = 0; m < 4; ++m)
      #pragma unroll
      for (int n = 0; n < 4; ++n)
        acc[m][n] = __builtin_amdgcn_mfma_f32_16x16x32_bf16(af[m], bfr[n], acc[m][n], 0, 0, 0);
    __syncthreads();
  }

  const int row0 = bm * 128 + wr + khi * 4;
  const int col0 = bn * 128 + wc + r16;

  if constexpr (MODE == 4) {
    // fused decode: logit[r] += sum_c (acc + bias[c]) * dec_w[c]
    float dwv[4], bvv[4];
    #pragma unroll
    for (int n = 0; n < 4; ++n) {
      int c = col0 + n * 16;
      dwv[n] = dw[c];
      bvv[n] = bias[c];
    }
    #pragma unroll
    for (int m = 0; m < 4; ++m) {
      #pragma unroll
      for (int j = 0; j < 4; ++j) {
        float p = 0.f;
        #pragma unroll
        for (int n = 0; n < 4; ++n) p += (acc[m][n][j] + bvv[n]) * dwv[n];
        p += __shfl_xor(p, 1);
        p += __shfl_xor(p, 2);
        p += __shfl_xor(p, 4);
        p += __shfl_xor(p, 8);
        if (r16 == 0) atomicAdd(&logit[row0 + m * 16 + j], p);
      }
    }
  } else {
    #pragma unroll
    for (int m = 0; m < 4; ++m) {
      #pragma unroll
      for (int n = 0; n < 4; ++n) {
        int c = col0 + n * 16;
        float bv = (MODE == 3) ? bias[c] : 0.f;
        #pragma unroll
        for (int j = 0; j < 4; ++j) {
          int r = row0 + m * 16 + j;
          Cb[(size_t)r * ldc + c] = f2bf(acc[m][n][j] + bv);
        }
      }
    }
  }
}

// ---------------------------------------------------------------------------
// seq-axis attention via MFMA. One wave = one (group g, head hd).
// QKV [NPOS][QLD] bf16 (q|k|v in cols 0..767). Writes Ob cols 0..255 (ld 768).
// ---------------------------------------------------------------------------
__global__ __launch_bounds__(256) void attn_seq_mfma(
    const u16* __restrict__ QKV, u16* __restrict__ Ob)
{
  const int w = threadIdx.x >> 6, lane = threadIdx.x & 63;
  const int wid = blockIdx.x * 4 + w;
  const int hd = wid & 15, g = wid >> 4;          // g in [0,640)
  const int gb = g / 20, gr = g % 20;
  const int nbase = gb * 1280 + gr;               // + pos*20
  const int lo = lane & 31, hi = lane >> 5;

  bf16x8 kf[2], qf[2];
  #pragma unroll
  for (int t = 0; t < 2; ++t) {
    size_t r = (size_t)(nbase + (lo + 32 * t) * 20) * QLD;
    kf[t] = *(const bf16x8*)(QKV + r + 256 + hd * 16 + hi * 8);
    qf[t] = *(const bf16x8*)(QKV + r +       hd * 16 + hi * 8);
  }
  union { u16 a[8]; bf16x8 v; } vt[4];
  #pragma unroll
  for (int c = 0; c < 4; ++c)
    #pragma unroll
    for (int j = 0; j < 8; ++j)
      vt[c].a[j] = QKV[(size_t)(nbase + (c * 16 + hi * 8 + j) * 20) * QLD
                       + 512 + hd * 16 + lo];

  f32x16 s00 = {}, s10 = {}, s01 = {}, s11 = {};   // s[kt][qt]
  s00 = __builtin_amdgcn_mfma_f32_32x32x16_bf16(kf[0], qf[0], s00, 0, 0, 0);
  s10 = __builtin_amdgcn_mfma_f32_32x32x16_bf16(kf[1], qf[0], s10, 0, 0, 0);
  s01 = __builtin_amdgcn_mfma_f32_32x32x16_bf16(kf[0], qf[1], s01, 0, 0, 0);
  s11 = __builtin_amdgcn_mfma_f32_32x32x16_bf16(kf[1], qf[1], s11, 0, 0, 0);

  auto run_qt = [&](f32x16 t0, f32x16 t1, int qt) {
    float m = -1e30f;
    #pragma unroll
    for (int r = 0; r < 16; ++r) { m = fmaxf(m, t0[r]); m = fmaxf(m, t1[r]); }
    m = fmaxf(m, __shfl_xor(m, 32));
    const float C = 1.4426950408889634f;           // log2(e); 0.25 folded in wq
    float mc = m * C;
    float sum = 0.f;
    #pragma unroll
    for (int r = 0; r < 16; ++r) {
      float p0 = __builtin_amdgcn_exp2f(t0[r] * C - mc);
      float p1 = __builtin_amdgcn_exp2f(t1[r] * C - mc);
      t0[r] = p0; t1[r] = p1; sum += p0; sum += p1;
    }
    sum += __shfl_xor(sum, 32);
    float inv = __builtin_amdgcn_rcpf(sum);
    #pragma unroll
    for (int r = 0; r < 16; ++r) { t0[r] *= inv; t1[r] *= inv; }

    f32x16 oa = {};
    #pragma unroll
    for (int c = 0; c < 4; ++c) {
      const int rb = 8 * (c & 1);
      const f32x16& tt = (c < 2) ? t0 : t1;
      unsigned X0 = pkbf(tt[rb + 0], tt[rb + 1]);
      unsigned X1 = pkbf(tt[rb + 2], tt[rb + 3]);
      unsigned Y0 = pkbf(tt[rb + 4], tt[rb + 5]);
      unsigned Y1 = pkbf(tt[rb + 6], tt[rb + 7]);
      unsigned X0p = __shfl_xor((int)X0, 32), X1p = __shfl_xor((int)X1, 32);
      unsigned Y0p = __shfl_xor((int)Y0, 32), Y1p = __shfl_xor((int)Y1, 32);
      union { unsigned u[4]; bf16x8 v; } pf;
      pf.u[0] = hi ? Y0p : X0;
      pf.u[1] = hi ? Y1p : X1;
      pf.u[2] = hi ? Y0  : X0p;
      pf.u[3] = hi ? Y1  : X1p;
      oa = __builtin_amdgcn_mfma_f32_32x32x16_bf16(vt[c].v, pf.v, oa, 0, 0, 0);
    }
    unsigned P0 = pkbf(oa[0], oa[1]);
    unsigned P1 = pkbf(oa[2], oa[3]);
    unsigned P2 = pkbf(oa[4], oa[5]);
    unsigned P3 = pkbf(oa[6], oa[7]);
    unsigned sP0 = __shfl_xor((int)P0, 32), sP1 = __shfl_xor((int)P1, 32);
    unsigned sP2 = __shfl_xor((int)P2, 32), sP3 = __shfl_xor((int)P3, 32);
    union { unsigned u[4]; u16x8 v; } ov;
    ov.u[0] = hi ? sP2 : P0;
    ov.u[1] = hi ? sP3 : P1;
    ov.u[2] = hi ? P2  : sP0;
    ov.u[3] = hi ? P3  : sP1;
    u16* po = Ob + (size_t)(nbase + (qt * 32 + lo) * 20) * 768 + hd * 16 + hi * 8;
    *(u16x8*)po = ov.v;
  };
  run_qt(s00, s10, 0);
  run_qt(s01, s11, 1);
}

// ---------------------------------------------------------------------------
// H (T=4, stride 5) and W (T=5, stride 1) attention, one thread per (n, head)
// ---------------------------------------------------------------------------
template<int T>
__device__ __forceinline__ void attn1(
    const u16* __restrict__ QKV, int n, int base, int stp, int hd,
    u16* __restrict__ po)
{
  const u16* qp = QKV + (size_t)n * QLD + hd * 16;
  u16x8 q0 = *(const u16x8*)(qp), q1 = *(const u16x8*)(qp + 8);
  float q[16];
  #pragma unroll
  for (int d = 0; d < 8; ++d) { q[d] = bf2f(q0[d]); q[d + 8] = bf2f(q1[d]); }

  float s[T];
  float m = -1e30f;
  #pragma unroll
  for (int j = 0; j < T; ++j) {
    const u16* kp = QKV + (size_t)(base + j * stp) * QLD + 256 + hd * 16;
    u16x8 k0 = *(const u16x8*)(kp), k1 = *(const u16x8*)(kp + 8);
    float a = 0.f;
    #pragma unroll
    for (int d = 0; d < 8; ++d) a += q[d] * bf2f(k0[d]) + q[d + 8] * bf2f(k1[d]);
    s[j] = a;
    m = fmaxf(m, a);
  }
  float sum = 0.f;
  float o[16];
  #pragma unroll
  for (int d = 0; d < 16; ++d) o[d] = 0.f;
  #pragma unroll
  for (int j = 0; j < T; ++j) {
    float pj = __expf(s[j] - m);
    sum += pj;
    const u16* vp = QKV + (size_t)(base + j * stp) * QLD + 512 + hd * 16;
    u16x8 w0 = *(const u16x8*)(vp), w1 = *(const u16x8*)(vp + 8);
    #pragma unroll
    for (int d = 0; d < 8; ++d) { o[d] += pj * bf2f(w0[d]); o[d + 8] += pj * bf2f(w1[d]); }
  }
  float inv = 1.0f / sum;
  u16x8 r0, r1;
  #pragma unroll
  for (int d = 0; d < 8; ++d) { r0[d] = f2bf(o[d] * inv); r1[d] = f2bf(o[d + 8] * inv); }
  *(u16x8*)(po)     = r0;
  *(u16x8*)(po + 8) = r1;
}

__global__ __launch_bounds__(256) void attn_hw(
    const u16* __restrict__ QKV, u16* __restrict__ Ob)
{
  const int tg = blockIdx.x * 256 + threadIdx.x;   // n*16 + hd
  const int hd = tg & 15, n = tg >> 4;
  int h  = (n % 20) / 5;
  int w5 = n % 5;
  attn1<4>(QKV,       n, n - h * 5, 5, hd, Ob + (size_t)n * 768 + 256 + hd * 16);
  attn1<5>(QKV + 768, n, n - w5,    1, hd, Ob + (size_t)n * 768 + 512 + hd * 16);
}

// ---------------------------------------------------------------------------
// final sigmoid over accumulated logits
// ---------------------------------------------------------------------------
__global__ __launch_bounds__(256) void sigmoid_kernel(
    const float* __restrict__ logit, const float* __restrict__ dec_b,
    float* __restrict__ out)
{
  int i = blockIdx.x * 256 + threadIdx.x;
  out[i] = 1.0f / (1.0f + __expf(-(logit[i] + dec_b[0])));
}

// ---------------------------------------------------------------------------
extern "C" void kernel_launch(void* const* d_in, const int* in_sizes, int n_in,
                              void* d_out, int out_size, void* d_ws, size_t ws_size,
                              hipStream_t stream) {
  const float* x     = (const float*)d_in[0];
  const float* pos_s = (const float*)d_in[1];
  const float* pos_h = (const float*)d_in[2];
  const float* pos_w = (const float*)d_in[3];
  const float* wq    = (const float*)d_in[4];   // (2,3,256,256)
  const float* wkv   = (const float*)d_in[5];   // (2,3,512,256)
  const float* wo_w  = (const float*)d_in[6];   // (2,3,256,256)
  const float* wo_b  = (const float*)d_in[7];   // (2,3,256)
  const float* dec_w = (const float*)d_in[8];   // (1,256)
  const float* dec_b = (const float*)d_in[9];   // (1,)
  float* out = (float*)d_out;

  char* ws = (char*)d_ws;
  u16*   xb    = (u16*)ws;                       // 20,971,520
  u16*   Ob    = (u16*)(ws + 20971520);          // 62,914,560
  u16*   QKV   = (u16*)(ws + 83886080);          // 40960*1536*2 = 125,829,120
  u16*   wqp   = (u16*)(ws + 209715200);         // 2,359,296
  u16*   wop   = (u16*)(ws + 212074496);         // 786,432
  float* bsum  = (float*)(ws + 212860928);       // 2,048
  float* logit = (float*)(ws + 212862976);       // 163,840  (end ~213 MB)

  prep_kernel<<<2048, 256, 0, stream>>>(x, pos_s, pos_h, pos_w, xb);
  pack_qkv<<<4608, 256, 0, stream>>>(wq, wkv, wqp);
  pack_wo<<<1536, 256, 0, stream>>>(wo_w, wop);
  pack_bias<<<2, 256, 0, stream>>>(wo_b, bsum);
  hipMemsetAsync(logit, 0, NPOS * sizeof(float), stream);

  for (int l = 0; l < 2; ++l) {
    // seq axis: QKV cols 0..767 (ldc 1536), then MFMA attention
    gemm_bt<0><<<dim3(320, 6), 256, 0, stream>>>(
        xb, wqp + (size_t)(l * 3) * 196608, QKV, nullptr, nullptr, nullptr, 256, QLD);
    attn_seq_mfma<<<2560, 256, 0, stream>>>(QKV, Ob);
    // H+W axes: one N=1536 GEMM (weight rows adjacent), one fused attention
    gemm_bt<0><<<dim3(320, 12), 256, 0, stream>>>(
        xb, wqp + (size_t)(l * 3 + 1) * 196608, QKV, nullptr, nullptr, nullptr, 256, QLD);
    attn_hw<<<2560, 256, 0, stream>>>(QKV, Ob);
    // merged out-projection (K=768)
    if (l == 0)
      gemm_bt<3><<<dim3(320, 2), 256, 0, stream>>>(
          Ob, wop, xb, bsum, nullptr, nullptr, 768, 256);
    else
      gemm_bt<4><<<dim3(320, 2), 256, 0, stream>>>(
          Ob, wop + 196608, nullptr, bsum + 256, dec_w, logit, 768, 0);
  }

  sigmoid_kernel<<<NPOS / 256, 256, 0, stream>>>(logit, dec_b, out);
}

// Round 5
// 354.674 us; speedup vs baseline: 24.4136x; 1.0354x over previous
//
#include <hip/hip_runtime.h>
#include <stdint.h>

typedef unsigned short u16;
typedef u16 u16x8 __attribute__((ext_vector_type(8)));
typedef __bf16 bf16x8 __attribute__((ext_vector_type(8)));
typedef float f32x4 __attribute__((ext_vector_type(4)));
typedef float f32x16 __attribute__((ext_vector_type(16)));

#define NE   256
#define NPOS 40960     // 32*64*4*5
#define QLD  1536      // QKV row stride

__device__ __forceinline__ float bf2f(u16 h) {
  union { unsigned u; float f; } c; c.u = ((unsigned)h) << 16; return c.f;
}
__device__ __forceinline__ u16 f2bf(float f) {
  union { float f; unsigned u; } c; c.f = f;
  unsigned u = c.u;
  return (u16)((u + 0x7FFFu + ((u >> 16) & 1u)) >> 16);
}
__device__ __forceinline__ unsigned pkbf(float a, float b) {
  unsigned r;
  asm("v_cvt_pk_bf16_f32 %0, %1, %2" : "=v"(r) : "v"(a), "v"(b));
  return r;
}
__device__ __forceinline__ void gll16(const void* g, void* l) {
  __builtin_amdgcn_global_load_lds(
      (const __attribute__((address_space(1))) void*)g,
      (__attribute__((address_space(3))) void*)l, 16, 0, 0);
}
template<int N> __device__ __forceinline__ void waitvm() {
  if constexpr (N == 0)      asm volatile("s_waitcnt vmcnt(0)" ::: "memory");
  else if constexpr (N == 4) asm volatile("s_waitcnt vmcnt(4)" ::: "memory");
  else if constexpr (N == 6) asm volatile("s_waitcnt vmcnt(6)" ::: "memory");
}

// ---------------------------------------------------------------------------
// prep: xb[n][e] = bf16(x[b,s,e,h,w] + pos), n = ((b*64+s)*4+h)*5+w
// ---------------------------------------------------------------------------
__global__ __launch_bounds__(256) void prep_kernel(
    const float* __restrict__ x, const float* __restrict__ pos_s,
    const float* __restrict__ pos_h, const float* __restrict__ pos_w,
    u16* __restrict__ xb)
{
  __shared__ float Ls[256 * 21];
  const int bs = blockIdx.x;           // b*64+s
  const int s  = bs & 63;
  const int tid = threadIdx.x;
  const float* xp = x + (size_t)bs * 5120;
  for (int i = tid; i < 5120; i += 256) {
    int e = i / 20, hw = i % 20;
    int h = hw / 5, w = hw % 5;
    float v = xp[i] + pos_s[s * 256 + e] + pos_h[e * 4 + h] + pos_w[e * 5 + w];
    Ls[e * 21 + hw] = v;
  }
  __syncthreads();
  u16* op = xb + (size_t)bs * 20 * 256;
  for (int i = tid; i < 5120; i += 256) {
    int nl = i >> 8, e = i & 255;
    op[nl * 256 + e] = f2bf(Ls[e * 21 + nl]);
  }
}

// ---------------------------------------------------------------------------
// weight packing; wq rows scaled by 0.25 (attention SCALE folded in)
// ---------------------------------------------------------------------------
__global__ __launch_bounds__(256) void pack_qkv(
    const float* __restrict__ wq, const float* __restrict__ wkv, u16* __restrict__ dst)
{
  int i = blockIdx.x * 256 + threadIdx.x;      // 6*768*256
  int la = i / (768 * 256);
  int rem = i - la * (768 * 256);
  int r = rem >> 8, c = rem & 255;
  float v = (r < 256) ? wq[(size_t)la * 65536 + r * 256 + c] * 0.25f
                      : wkv[(size_t)la * 131072 + (r - 256) * 256 + c];
  dst[i] = f2bf(v);
}

// merged out-proj weights: dst[l][out][a*256+in] = wo_w[l][a][out][in]
__global__ __launch_bounds__(256) void pack_wo(
    const float* __restrict__ wo, u16* __restrict__ dst)
{
  int i = blockIdx.x * 256 + threadIdx.x;      // 2*256*768
  int l = i / 196608;
  int rem = i - l * 196608;
  int out = rem / 768, k = rem % 768;
  int a = k >> 8, in = k & 255;
  dst[i] = f2bf(wo[(size_t)(((l * 3 + a) * 256) + out) * 256 + in]);
}

__global__ __launch_bounds__(256) void pack_bias(
    const float* __restrict__ wo_b, float* __restrict__ bsum)
{
  int i = blockIdx.x * 256 + threadIdx.x;      // 512
  if (i < 512) {
    int l = i >> 8, c = i & 255;
    bsum[i] = wo_b[(l * 3 + 0) * 256 + c] + wo_b[(l * 3 + 1) * 256 + c]
            + wo_b[(l * 3 + 2) * 256 + c];
  }
}

// ---------------------------------------------------------------------------
// GEMM: C[M][N] = A[M][K] * B[N][K]^T   (A,B bf16; acc f32)
// 128 x BN tile, K = NKT*32, double-buffered LDS, counted-vmcnt prefetch.
// MODE 0: store bf16 at ldc; 3: Cb = bf16(acc+bias); 4: fused decode partial
// ---------------------------------------------------------------------------
template<int MODE, int BN, int NKT>
__global__ __launch_bounds__(256, 2) void gemm_bt(
    const u16* __restrict__ A, const u16* __restrict__ B,
    u16* __restrict__ Cb, const float* __restrict__ bias,
    const float* __restrict__ dw, float* __restrict__ logit,
    int ldc)
{
  constexpr int K   = NKT * 32;
  constexpr int NF  = BN / 32;          // n-frags per wave (wave covers BN/2)
  constexpr int LPT = 2 + BN / 64;      // gll16 per thread per k-tile
  static_assert(MODE != 4 || BN == 128, "");

  __shared__ alignas(16) u16 As[2][128 * 32];
  __shared__ alignas(16) u16 Bs[2][BN * 32];

  const int tid  = threadIdx.x;
  const int bm   = blockIdx.x, bn = blockIdx.y;
  const int lane = tid & 63, w = tid >> 6;
  const int wr   = (w >> 1) * 64, wc = (w & 1) * (BN / 2);
  const int r16  = lane & 15, khi = lane >> 4;

  f32x4 acc[4][NF] = {};

  const u16* gA = A + (size_t)bm * 128 * K;
  const u16* gB = B + (size_t)bn * BN * K;

  auto STAGE = [&](int kt, int which) {
    const u16* tA = gA + kt * 32;
    const u16* tB = gB + kt * 32;
    #pragma unroll
    for (int r = 0; r < 2; ++r) {
      int i = tid + r * 256;             // 0..511
      int row = i >> 2, seg = (i & 3) << 3;
      gll16(tA + (size_t)row * K + seg, (char*)&As[which][0] + i * 16);
    }
    #pragma unroll
    for (int r = 0; r < BN / 64; ++r) {
      int i = tid + r * 256;             // 0..BN*4-1
      int row = i >> 2, seg = (i & 3) << 3;
      gll16(tB + (size_t)row * K + seg, (char*)&Bs[which][0] + i * 16);
    }
  };

  STAGE(0, 0);
  #pragma unroll
  for (int kt = 0; kt < NKT; ++kt) {
    const int cur = kt & 1;
    if (kt + 1 < NKT) { STAGE(kt + 1, cur ^ 1); waitvm<LPT>(); }
    else              { waitvm<0>(); }
    __builtin_amdgcn_s_barrier();
    asm volatile("" ::: "memory");

    bf16x8 af[4], bfr[NF];
    #pragma unroll
    for (int m = 0; m < 4; ++m)
      af[m] = *(const bf16x8*)(&As[cur][0] + (wr + m * 16 + r16) * 32 + khi * 8);
    #pragma unroll
    for (int n = 0; n < NF; ++n)
      bfr[n] = *(const bf16x8*)(&Bs[cur][0] + (wc + n * 16 + r16) * 32 + khi * 8);
    #pragma unroll
    for (int m = 0; m < 4; ++m)
      #pragma unroll
      for (int n = 0; n < NF; ++n)
        acc[m][n] = __builtin_amdgcn_mfma_f32_16x16x32_bf16(af[m], bfr[n], acc[m][n], 0, 0, 0);

    asm volatile("" ::: "memory");
    __builtin_amdgcn_s_barrier();
  }

  const int row0 = bm * 128 + wr + khi * 4;
  const int col0 = bn * BN + wc + r16;

  if constexpr (MODE == 4) {
    // fused decode: logit[r] += sum_c (acc + bias[c]) * dec_w[c]
    float dwv[NF], bvv[NF];
    #pragma unroll
    for (int n = 0; n < NF; ++n) {
      int c = col0 + n * 16;
      dwv[n] = dw[c];
      bvv[n] = bias[c];
    }
    #pragma unroll
    for (int m = 0; m < 4; ++m) {
      #pragma unroll
      for (int j = 0; j < 4; ++j) {
        float p = 0.f;
        #pragma unroll
        for (int n = 0; n < NF; ++n) p += (acc[m][n][j] + bvv[n]) * dwv[n];
        p += __shfl_xor(p, 1);
        p += __shfl_xor(p, 2);
        p += __shfl_xor(p, 4);
        p += __shfl_xor(p, 8);
        if (r16 == 0) atomicAdd(&logit[row0 + m * 16 + j], p);
      }
    }
  } else {
    #pragma unroll
    for (int m = 0; m < 4; ++m) {
      #pragma unroll
      for (int n = 0; n < NF; ++n) {
        int c = col0 + n * 16;
        float bv = (MODE == 3) ? bias[c] : 0.f;
        #pragma unroll
        for (int j = 0; j < 4; ++j) {
          int r = row0 + m * 16 + j;
          Cb[(size_t)r * ldc + c] = f2bf(acc[m][n][j] + bv);
        }
      }
    }
  }
}

// ---------------------------------------------------------------------------
// seq-axis attention via MFMA. One wave = one (group g, head hd).
// QKV [NPOS][QLD] bf16 (q|k|v in cols 0..767). Writes Ob cols 0..255 (ld 768).
// ---------------------------------------------------------------------------
__global__ __launch_bounds__(256) void attn_seq_mfma(
    const u16* __restrict__ QKV, u16* __restrict__ Ob)
{
  const int w = threadIdx.x >> 6, lane = threadIdx.x & 63;
  const int wid = blockIdx.x * 4 + w;
  const int hd = wid & 15, g = wid >> 4;          // g in [0,640)
  const int gb = g / 20, gr = g % 20;
  const int nbase = gb * 1280 + gr;               // + pos*20
  const int lo = lane & 31, hi = lane >> 5;

  bf16x8 kf[2], qf[2];
  #pragma unroll
  for (int t = 0; t < 2; ++t) {
    size_t r = (size_t)(nbase + (lo + 32 * t) * 20) * QLD;
    kf[t] = *(const bf16x8*)(QKV + r + 256 + hd * 16 + hi * 8);
    qf[t] = *(const bf16x8*)(QKV + r +       hd * 16 + hi * 8);
  }
  union { u16 a[8]; bf16x8 v; } vt[4];
  #pragma unroll
  for (int c = 0; c < 4; ++c)
    #pragma unroll
    for (int j = 0; j < 8; ++j)
      vt[c].a[j] = QKV[(size_t)(nbase + (c * 16 + hi * 8 + j) * 20) * QLD
                       + 512 + hd * 16 + lo];

  f32x16 s00 = {}, s10 = {}, s01 = {}, s11 = {};   // s[kt][qt]
  s00 = __builtin_amdgcn_mfma_f32_32x32x16_bf16(kf[0], qf[0], s00, 0, 0, 0);
  s10 = __builtin_amdgcn_mfma_f32_32x32x16_bf16(kf[1], qf[0], s10, 0, 0, 0);
  s01 = __builtin_amdgcn_mfma_f32_32x32x16_bf16(kf[0], qf[1], s01, 0, 0, 0);
  s11 = __builtin_amdgcn_mfma_f32_32x32x16_bf16(kf[1], qf[1], s11, 0, 0, 0);

  auto run_qt = [&](f32x16 t0, f32x16 t1, int qt) {
    float m = -1e30f;
    #pragma unroll
    for (int r = 0; r < 16; ++r) { m = fmaxf(m, t0[r]); m = fmaxf(m, t1[r]); }
    m = fmaxf(m, __shfl_xor(m, 32));
    const float C = 1.4426950408889634f;           // log2(e); 0.25 folded in wq
    float mc = m * C;
    float sum = 0.f;
    #pragma unroll
    for (int r = 0; r < 16; ++r) {
      float p0 = __builtin_amdgcn_exp2f(t0[r] * C - mc);
      float p1 = __builtin_amdgcn_exp2f(t1[r] * C - mc);
      t0[r] = p0; t1[r] = p1; sum += p0; sum += p1;
    }
    sum += __shfl_xor(sum, 32);
    float inv = __builtin_amdgcn_rcpf(sum);
    #pragma unroll
    for (int r = 0; r < 16; ++r) { t0[r] *= inv; t1[r] *= inv; }

    f32x16 oa = {};
    #pragma unroll
    for (int c = 0; c < 4; ++c) {
      const int rb = 8 * (c & 1);
      const f32x16& tt = (c < 2) ? t0 : t1;
      unsigned X0 = pkbf(tt[rb + 0], tt[rb + 1]);
      unsigned X1 = pkbf(tt[rb + 2], tt[rb + 3]);
      unsigned Y0 = pkbf(tt[rb + 4], tt[rb + 5]);
      unsigned Y1 = pkbf(tt[rb + 6], tt[rb + 7]);
      unsigned X0p = __shfl_xor((int)X0, 32), X1p = __shfl_xor((int)X1, 32);
      unsigned Y0p = __shfl_xor((int)Y0, 32), Y1p = __shfl_xor((int)Y1, 32);
      union { unsigned u[4]; bf16x8 v; } pf;
      pf.u[0] = hi ? Y0p : X0;
      pf.u[1] = hi ? Y1p : X1;
      pf.u[2] = hi ? Y0  : X0p;
      pf.u[3] = hi ? Y1  : X1p;
      oa = __builtin_amdgcn_mfma_f32_32x32x16_bf16(vt[c].v, pf.v, oa, 0, 0, 0);
    }
    unsigned P0 = pkbf(oa[0], oa[1]);
    unsigned P1 = pkbf(oa[2], oa[3]);
    unsigned P2 = pkbf(oa[4], oa[5]);
    unsigned P3 = pkbf(oa[6], oa[7]);
    unsigned sP0 = __shfl_xor((int)P0, 32), sP1 = __shfl_xor((int)P1, 32);
    unsigned sP2 = __shfl_xor((int)P2, 32), sP3 = __shfl_xor((int)P3, 32);
    union { unsigned u[4]; u16x8 v; } ov;
    ov.u[0] = hi ? sP2 : P0;
    ov.u[1] = hi ? sP3 : P1;
    ov.u[2] = hi ? P2  : sP0;
    ov.u[3] = hi ? P3  : sP1;
    u16* po = Ob + (size_t)(nbase + (qt * 32 + lo) * 20) * 768 + hd * 16 + hi * 8;
    *(u16x8*)po = ov.v;
  };
  run_qt(s00, s10, 0);
  run_qt(s01, s11, 1);
}

// ---------------------------------------------------------------------------
// H (T=4, stride 5) and W (T=5, stride 1) attention, one thread per (n, head)
// ---------------------------------------------------------------------------
template<int T>
__device__ __forceinline__ void attn1(
    const u16* __restrict__ QKV, int n, int base, int stp, int hd,
    u16* __restrict__ po)
{
  const u16* qp = QKV + (size_t)n * QLD + hd * 16;
  u16x8 q0 = *(const u16x8*)(qp), q1 = *(const u16x8*)(qp + 8);
  float q[16];
  #pragma unroll
  for (int d = 0; d < 8; ++d) { q[d] = bf2f(q0[d]); q[d + 8] = bf2f(q1[d]); }

  float s[T];
  float m = -1e30f;
  #pragma unroll
  for (int j = 0; j < T; ++j) {
    const u16* kp = QKV + (size_t)(base + j * stp) * QLD + 256 + hd * 16;
    u16x8 k0 = *(const u16x8*)(kp), k1 = *(const u16x8*)(kp + 8);
    float a = 0.f;
    #pragma unroll
    for (int d = 0; d < 8; ++d) a += q[d] * bf2f(k0[d]) + q[d + 8] * bf2f(k1[d]);
    s[j] = a;
    m = fmaxf(m, a);
  }
  float sum = 0.f;
  float o[16];
  #pragma unroll
  for (int d = 0; d < 16; ++d) o[d] = 0.f;
  #pragma unroll
  for (int j = 0; j < T; ++j) {
    float pj = __expf(s[j] - m);
    sum += pj;
    const u16* vp = QKV + (size_t)(base + j * stp) * QLD + 512 + hd * 16;
    u16x8 w0 = *(const u16x8*)(vp), w1 = *(const u16x8*)(vp + 8);
    #pragma unroll
    for (int d = 0; d < 8; ++d) { o[d] += pj * bf2f(w0[d]); o[d + 8] += pj * bf2f(w1[d]); }
  }
  float inv = 1.0f / sum;
  u16x8 r0, r1;
  #pragma unroll
  for (int d = 0; d < 8; ++d) { r0[d] = f2bf(o[d] * inv); r1[d] = f2bf(o[d + 8] * inv); }
  *(u16x8*)(po)     = r0;
  *(u16x8*)(po + 8) = r1;
}

__global__ __launch_bounds__(256) void attn_hw(
    const u16* __restrict__ QKV, u16* __restrict__ Ob)
{
  const int tg = blockIdx.x * 256 + threadIdx.x;   // n*16 + hd
  const int hd = tg & 15, n = tg >> 4;
  int h  = (n % 20) / 5;
  int w5 = n % 5;
  attn1<4>(QKV,       n, n - h * 5, 5, hd, Ob + (size_t)n * 768 + 256 + hd * 16);
  attn1<5>(QKV + 768, n, n - w5,    1, hd, Ob + (size_t)n * 768 + 512 + hd * 16);
}

// ---------------------------------------------------------------------------
// final sigmoid over accumulated logits
// ---------------------------------------------------------------------------
__global__ __launch_bounds__(256) void sigmoid_kernel(
    const float* __restrict__ logit, const float* __restrict__ dec_b,
    float* __restrict__ out)
{
  int i = blockIdx.x * 256 + threadIdx.x;
  out[i] = 1.0f / (1.0f + __expf(-(logit[i] + dec_b[0])));
}

// ---------------------------------------------------------------------------
extern "C" void kernel_launch(void* const* d_in, const int* in_sizes, int n_in,
                              void* d_out, int out_size, void* d_ws, size_t ws_size,
                              hipStream_t stream) {
  const float* x     = (const float*)d_in[0];
  const float* pos_s = (const float*)d_in[1];
  const float* pos_h = (const float*)d_in[2];
  const float* pos_w = (const float*)d_in[3];
  const float* wq    = (const float*)d_in[4];   // (2,3,256,256)
  const float* wkv   = (const float*)d_in[5];   // (2,3,512,256)
  const float* wo_w  = (const float*)d_in[6];   // (2,3,256,256)
  const float* wo_b  = (const float*)d_in[7];   // (2,3,256)
  const float* dec_w = (const float*)d_in[8];   // (1,256)
  const float* dec_b = (const float*)d_in[9];   // (1,)
  float* out = (float*)d_out;

  char* ws = (char*)d_ws;
  u16*   xb    = (u16*)ws;                       // 20,971,520
  u16*   Ob    = (u16*)(ws + 20971520);          // 62,914,560
  u16*   QKV   = (u16*)(ws + 83886080);          // 40960*1536*2 = 125,829,120
  u16*   wqp   = (u16*)(ws + 209715200);         // 2,359,296
  u16*   wop   = (u16*)(ws + 212074496);         // 786,432
  float* bsum  = (float*)(ws + 212860928);       // 2,048
  float* logit = (float*)(ws + 212862976);       // 163,840  (end ~213 MB)

  prep_kernel<<<2048, 256, 0, stream>>>(x, pos_s, pos_h, pos_w, xb);
  pack_qkv<<<4608, 256, 0, stream>>>(wq, wkv, wqp);
  pack_wo<<<1536, 256, 0, stream>>>(wo_w, wop);
  pack_bias<<<2, 256, 0, stream>>>(wo_b, bsum);
  hipMemsetAsync(logit, 0, NPOS * sizeof(float), stream);

  for (int l = 0; l < 2; ++l) {
    // seq axis: QKV cols 0..767 (ldc 1536), then MFMA attention
    gemm_bt<0, 256, 8><<<dim3(320, 3), 256, 0, stream>>>(
        xb, wqp + (size_t)(l * 3) * 196608, QKV, nullptr, nullptr, nullptr, QLD);
    attn_seq_mfma<<<2560, 256, 0, stream>>>(QKV, Ob);
    // H+W axes: one N=1536 GEMM (weight rows adjacent), one fused attention
    gemm_bt<0, 256, 8><<<dim3(320, 6), 256, 0, stream>>>(
        xb, wqp + (size_t)(l * 3 + 1) * 196608, QKV, nullptr, nullptr, nullptr, QLD);
    attn_hw<<<2560, 256, 0, stream>>>(QKV, Ob);
    // merged out-projection (K=768)
    if (l == 0)
      gemm_bt<3, 128, 24><<<dim3(320, 2), 256, 0, stream>>>(
          Ob, wop, xb, bsum, nullptr, nullptr, 256);
    else
      gemm_bt<4, 128, 24><<<dim3(320, 2), 256, 0, stream>>>(
          Ob, wop + 196608, nullptr, bsum + 256, dec_w, logit, 0);
  }

  sigmoid_kernel<<<NPOS / 256, 256, 0, stream>>>(logit, dec_b, out);
}